// Round 1
// baseline (826.250 us; speedup 1.0000x reference)
//
#include <hip/hip_runtime.h>

#define N_NODES 50000
#define F 128
#define TILE_M 32

// ---------------------------------------------------------------------------
// Phase 1: edge aggregation.  One wave (64 lanes) per edge; each lane handles
// 2 consecutive features (float2).  Gather x[src] (coalesced 512B/edge),
// scatter-add into sums[dst] with f32 atomics.  Lane 0 counts degree.
// ---------------------------------------------------------------------------
__global__ __launch_bounds__(256) void agg_kernel(
    const float* __restrict__ x,
    const int* __restrict__ src,
    const int* __restrict__ dst,
    float* __restrict__ sums,
    int* __restrict__ deg,
    int E)
{
    const int gtid   = blockIdx.x * blockDim.x + threadIdx.x;
    const int wave   = gtid >> 6;
    const int lane   = threadIdx.x & 63;
    const int nwaves = (gridDim.x * blockDim.x) >> 6;

    for (int e = wave; e < E; e += nwaves) {
        const int s = src[e];
        const int d = dst[e];
        const float2 v =
            *reinterpret_cast<const float2*>(&x[(size_t)s * F + 2 * lane]);
        float* p = &sums[(size_t)d * F + 2 * lane];
        atomicAdd(p,     v.x);
        atomicAdd(p + 1, v.y);
        if (lane == 0) atomicAdd(&deg[d], 1);
    }
}

// ---------------------------------------------------------------------------
// Phase 2: out[i] = (sums[i]/max(deg[i],1)) @ W_l + x[i] @ W_r + b
// sums lives in d_out; each block owns TILE_M rows, stages mean & x rows in
// LDS, then each thread computes 16 (row, col) outputs.  In-place safe: a
// block reads only the rows it writes, and reads complete before writes.
// ---------------------------------------------------------------------------
__global__ __launch_bounds__(256) void out_kernel(
    const float* __restrict__ x,
    const float* __restrict__ Wl,
    const float* __restrict__ Wr,
    const float* __restrict__ b,
    const int* __restrict__ deg,
    float* __restrict__ out /* holds sums on entry */)
{
    __shared__ float mean_s[TILE_M][F];
    __shared__ float x_s[TILE_M][F];
    __shared__ float invdeg_s[TILE_M];

    const int base = blockIdx.x * TILE_M;
    const int t = threadIdx.x;

    if (t < TILE_M) {
        const int r = base + t;
        int dg = (r < N_NODES) ? deg[r] : 1;
        if (dg < 1) dg = 1;
        invdeg_s[t] = 1.0f / (float)dg;
    }
    __syncthreads();

    // Stage 32x128 sums (scaled to mean) and x rows: 16 elements per thread.
#pragma unroll
    for (int j = 0; j < TILE_M * F / 256; ++j) {
        const int idx = t + j * 256;
        const int r = idx >> 7;     // /F
        const int c = idx & (F - 1);
        const int gr = base + r;
        float sv = 0.f, xv = 0.f;
        if (gr < N_NODES) {
            sv = out[(size_t)gr * F + c] * invdeg_s[r];
            xv = x[(size_t)gr * F + c];
        }
        mean_s[r][c] = sv;
        x_s[r][c] = xv;
    }
    __syncthreads();

    const int col  = t & (F - 1);
    const int half = t >> 7;              // 0 or 1 -> rows [0..15] / [16..31]

    float acc[TILE_M / 2];
#pragma unroll
    for (int m = 0; m < TILE_M / 2; ++m) acc[m] = 0.f;

    for (int k = 0; k < F; ++k) {
        const float wl = Wl[k * F + col];
        const float wr = Wr[k * F + col];
#pragma unroll
        for (int m = 0; m < TILE_M / 2; ++m) {
            const int r = half * (TILE_M / 2) + m;
            acc[m] += mean_s[r][k] * wl + x_s[r][k] * wr;
        }
    }

    const float bias = b[col];
#pragma unroll
    for (int m = 0; m < TILE_M / 2; ++m) {
        const int r = half * (TILE_M / 2) + m;
        const int gr = base + r;
        if (gr < N_NODES) out[(size_t)gr * F + col] = acc[m] + bias;
    }
}

extern "C" void kernel_launch(void* const* d_in, const int* in_sizes, int n_in,
                              void* d_out, int out_size, void* d_ws, size_t ws_size,
                              hipStream_t stream)
{
    const float* x  = (const float*)d_in[0];
    const int*   ei = (const int*)d_in[1];
    const float* Wl = (const float*)d_in[2];
    const float* Wr = (const float*)d_in[3];
    const float* b  = (const float*)d_in[4];
    float* out = (float*)d_out;

    const int E = in_sizes[1] / 2;
    const int* src = ei;
    const int* dst = ei + E;

    int* deg = (int*)d_ws;

    // Zero the accumulation buffers each call (harness poisons with 0xAA).
    hipMemsetAsync(d_out, 0, (size_t)N_NODES * F * sizeof(float), stream);
    hipMemsetAsync(deg, 0, (size_t)N_NODES * sizeof(int), stream);

    agg_kernel<<<2048, 256, 0, stream>>>(x, src, dst, out, deg, E);

    const int nblocks = (N_NODES + TILE_M - 1) / TILE_M;
    out_kernel<<<nblocks, 256, 0, stream>>>(x, Wl, Wr, b, deg, out);
}

// Round 4
// 452.596 us; speedup vs baseline: 1.8256x; 1.8256x over previous
//
#include <hip/hip_runtime.h>

#define N_NODES 50000
#define F 128
#define TILE_M 32

// ---------------------------------------------------------------------------
// Phase 1a: degree histogram (int atomics only).
// ---------------------------------------------------------------------------
__global__ __launch_bounds__(256) void hist_kernel(
    const int* __restrict__ dst, int* __restrict__ deg, int E)
{
    const int e = blockIdx.x * 256 + threadIdx.x;
    if (e < E) atomicAdd(&deg[dst[e]], 1);
}

// ---------------------------------------------------------------------------
// Phase 1b: single-block exclusive scan of deg -> start[0..n], cursor copy.
// 256 threads (4 waves); shfl inclusive scan per wave + serial wave combine.
// ---------------------------------------------------------------------------
__global__ __launch_bounds__(256) void scan_kernel(
    const int* __restrict__ deg,
    int* __restrict__ start,
    int* __restrict__ cursor,
    int n)
{
    __shared__ int wsum[4];
    __shared__ int carry_s;
    const int t = threadIdx.x;
    const int lane = t & 63;
    const int wid = t >> 6;

    if (t == 0) carry_s = 0;
    __syncthreads();

    for (int base = 0; base < n; base += 256) {
        const int i = base + t;
        const int v = (i < n) ? deg[i] : 0;
        int incl = v;
#pragma unroll
        for (int off = 1; off < 64; off <<= 1) {
            const int u = __shfl_up(incl, off, 64);
            if (lane >= off) incl += u;
        }
        if (lane == 63) wsum[wid] = incl;
        __syncthreads();
        if (t == 0) {
            int run = carry_s;
#pragma unroll
            for (int w = 0; w < 4; ++w) {
                const int s = wsum[w];
                wsum[w] = run;      // exclusive prefix (incl. carry)
                run += s;
            }
            carry_s = run;
        }
        __syncthreads();
        const int excl = wsum[wid] + incl - v;
        if (i < n) { start[i] = excl; cursor[i] = excl; }
        __syncthreads();
    }
    if (t == 0) start[n] = carry_s;
}

// ---------------------------------------------------------------------------
// Phase 1c: scatter edges into CSR buckets (int atomics only).
// ---------------------------------------------------------------------------
__global__ __launch_bounds__(256) void scatter_kernel(
    const int* __restrict__ src, const int* __restrict__ dst,
    int* __restrict__ cursor, int* __restrict__ csr_src, int E)
{
    const int e = blockIdx.x * 256 + threadIdx.x;
    if (e < E) {
        const int pos = atomicAdd(&cursor[dst[e]], 1);
        csr_src[pos] = src[e];
    }
}

// ---------------------------------------------------------------------------
// Phase 2: per-node mean aggregation, no f32 atomics.  128 threads per node
// (2 nodes per 256-thread block); each thread owns one feature column.
// Gathers of x[s] are 512B contiguous per node -> coalesced; x (25.6 MB)
// lives in L2/L3.
// ---------------------------------------------------------------------------
__global__ __launch_bounds__(256) void aggregate_kernel(
    const float* __restrict__ x,
    const int* __restrict__ start,
    const int* __restrict__ csr_src,
    float* __restrict__ mean, int nnodes)
{
    const int group = threadIdx.x >> 7;
    const int col = threadIdx.x & 127;
    const int node = blockIdx.x * 2 + group;
    if (node >= nnodes) return;

    const int s0 = start[node];
    const int s1 = start[node + 1];
    float acc = 0.f;
    for (int j = s0; j < s1; ++j) {
        const int s = csr_src[j];
        acc += x[(size_t)s * F + col];
    }
    const int d = s1 - s0;
    const float inv = (d > 0) ? (1.0f / (float)d) : 1.0f;
    mean[(size_t)node * F + col] = acc * inv;
}

// ---------------------------------------------------------------------------
// Phase 3: out[i] = mean[i] @ W_l + x[i] @ W_r + b   (mean lives in d_out,
// written in place).  k unrolled by 4 with float4 LDS broadcasts.
// ---------------------------------------------------------------------------
__global__ __launch_bounds__(256) void out_kernel(
    const float* __restrict__ x,
    const float* __restrict__ Wl,
    const float* __restrict__ Wr,
    const float* __restrict__ b,
    float* __restrict__ out /* holds mean on entry */)
{
    __shared__ float mean_s[TILE_M][F];
    __shared__ float x_s[TILE_M][F];

    const int base = blockIdx.x * TILE_M;
    const int t = threadIdx.x;

    // Stage 32x128 mean and x rows: 4 float4 per thread per array.
#pragma unroll
    for (int j = 0; j < (TILE_M * F / 4) / 256; ++j) {
        const int idx = t + j * 256;          // float4 index
        const int r = idx >> 5;               // 32 float4 per row
        const int c4 = (idx & 31) * 4;
        const int gr = base + r;
        float4 mv = make_float4(0.f, 0.f, 0.f, 0.f);
        float4 xv = make_float4(0.f, 0.f, 0.f, 0.f);
        if (gr < N_NODES) {
            mv = *reinterpret_cast<const float4*>(&out[(size_t)gr * F + c4]);
            xv = *reinterpret_cast<const float4*>(&x[(size_t)gr * F + c4]);
        }
        *reinterpret_cast<float4*>(&mean_s[r][c4]) = mv;
        *reinterpret_cast<float4*>(&x_s[r][c4]) = xv;
    }
    __syncthreads();

    const int col = t & (F - 1);
    const int half = t >> 7;

    float acc[TILE_M / 2];
#pragma unroll
    for (int m = 0; m < TILE_M / 2; ++m) acc[m] = 0.f;

    for (int k = 0; k < F; k += 4) {
        const float wl0 = Wl[(k + 0) * F + col];
        const float wl1 = Wl[(k + 1) * F + col];
        const float wl2 = Wl[(k + 2) * F + col];
        const float wl3 = Wl[(k + 3) * F + col];
        const float wr0 = Wr[(k + 0) * F + col];
        const float wr1 = Wr[(k + 1) * F + col];
        const float wr2 = Wr[(k + 2) * F + col];
        const float wr3 = Wr[(k + 3) * F + col];
#pragma unroll
        for (int m = 0; m < TILE_M / 2; ++m) {
            const int r = half * (TILE_M / 2) + m;
            const float4 mv = *reinterpret_cast<const float4*>(&mean_s[r][k]);
            const float4 xv = *reinterpret_cast<const float4*>(&x_s[r][k]);
            acc[m] += mv.x * wl0 + mv.y * wl1 + mv.z * wl2 + mv.w * wl3
                    + xv.x * wr0 + xv.y * wr1 + xv.z * wr2 + xv.w * wr3;
        }
    }

    const float bias = b[col];
#pragma unroll
    for (int m = 0; m < TILE_M / 2; ++m) {
        const int r = half * (TILE_M / 2) + m;
        const int gr = base + r;
        if (gr < N_NODES) out[(size_t)gr * F + col] = acc[m] + bias;
    }
}

extern "C" void kernel_launch(void* const* d_in, const int* in_sizes, int n_in,
                              void* d_out, int out_size, void* d_ws, size_t ws_size,
                              hipStream_t stream)
{
    const float* x  = (const float*)d_in[0];
    const int*   ei = (const int*)d_in[1];
    const float* Wl = (const float*)d_in[2];
    const float* Wr = (const float*)d_in[3];
    const float* b  = (const float*)d_in[4];
    float* out = (float*)d_out;

    const int E = in_sizes[1] / 2;
    const int* src = ei;
    const int* dst = ei + E;

    // Workspace layout (ints), 64-aligned chunks.
    int* deg     = (int*)d_ws;                 // 50000
    int* start   = deg + 50048;                // 50001
    int* cursor  = start + 50064;              // 50000
    int* csr_src = cursor + 50048;             // E

    hipMemsetAsync(deg, 0, (size_t)N_NODES * sizeof(int), stream);

    hist_kernel<<<(E + 255) / 256, 256, 0, stream>>>(dst, deg, E);
    scan_kernel<<<1, 256, 0, stream>>>(deg, start, cursor, N_NODES);
    scatter_kernel<<<(E + 255) / 256, 256, 0, stream>>>(src, dst, cursor, csr_src, E);
    aggregate_kernel<<<N_NODES / 2, 256, 0, stream>>>(x, start, csr_src, out, N_NODES);

    const int nblocks = (N_NODES + TILE_M - 1) / TILE_M;
    out_kernel<<<nblocks, 256, 0, stream>>>(x, Wl, Wr, b, out);
}

// Round 5
// 224.404 us; speedup vs baseline: 3.6820x; 2.0169x over previous
//
#include <hip/hip_runtime.h>

#define N_NODES 50000
#define F 128
#define E_FIXED 800000

typedef __attribute__((ext_vector_type(8))) short bf16x8;
typedef __attribute__((ext_vector_type(4))) float f32x4;

__device__ __forceinline__ unsigned short f2bf(float f) {
    unsigned u = __float_as_uint(f);
    unsigned r = u + 0x7FFFu + ((u >> 16) & 1u);   // RNE
    return (unsigned short)(r >> 16);
}

// ---------------------------------------------------------------------------
// x (fp32, N x 128) -> bf16
// ---------------------------------------------------------------------------
__global__ __launch_bounds__(256) void convert_x_kernel(
    const float* __restrict__ x, unsigned short* __restrict__ xb, int n4)
{
    const int i = blockIdx.x * 256 + threadIdx.x;
    if (i < n4) {
        const float4 v = reinterpret_cast<const float4*>(x)[i];
        ushort4 o;
        o.x = f2bf(v.x); o.y = f2bf(v.y); o.z = f2bf(v.z); o.w = f2bf(v.w);
        reinterpret_cast<ushort4*>(xb)[i] = o;
    }
}

// ---------------------------------------------------------------------------
// Bt[n][k] = bf16( k<128 ? Wl[k][n] : Wr[k-128][n] )   (128 x 256, K-contig)
// ---------------------------------------------------------------------------
__global__ __launch_bounds__(256) void convert_bt_kernel(
    const float* __restrict__ Wl, const float* __restrict__ Wr,
    unsigned short* __restrict__ Bt)
{
    const int gid = blockIdx.x * 256 + threadIdx.x;   // 32768 total
    const int n = gid >> 8;
    const int k = gid & 255;
    const float v = (k < F) ? Wl[k * F + n] : Wr[(k - F) * F + n];
    Bt[gid] = f2bf(v);
}

// ---------------------------------------------------------------------------
// degree histogram (int atomics)
// ---------------------------------------------------------------------------
__global__ __launch_bounds__(256) void hist_kernel(
    const int* __restrict__ dst, int* __restrict__ deg, int E)
{
    const int e = blockIdx.x * 256 + threadIdx.x;
    if (e < E) atomicAdd(&deg[dst[e]], 1);
}

// ---------------------------------------------------------------------------
// scan phase 1: per-block (256-wide) exclusive scan + block sums
// ---------------------------------------------------------------------------
__global__ __launch_bounds__(256) void scan_local_kernel(
    const int* __restrict__ deg, int* __restrict__ excl,
    int* __restrict__ bsum, int n)
{
    __shared__ int wsum[4];
    const int t = threadIdx.x, lane = t & 63, wid = t >> 6;
    const int i = blockIdx.x * 256 + t;
    const int v = (i < n) ? deg[i] : 0;
    int incl = v;
#pragma unroll
    for (int off = 1; off < 64; off <<= 1) {
        const int u = __shfl_up(incl, off, 64);
        if (lane >= off) incl += u;
    }
    if (lane == 63) wsum[wid] = incl;
    __syncthreads();
    if (t == 0) {
        int run = 0;
#pragma unroll
        for (int w = 0; w < 4; ++w) { const int s = wsum[w]; wsum[w] = run; run += s; }
        bsum[blockIdx.x] = run;
    }
    __syncthreads();
    if (i < n) excl[i] = wsum[wid] + incl - v;
}

// ---------------------------------------------------------------------------
// scan phase 2: exclusive scan of the <=256 block sums; writes grand total
// ---------------------------------------------------------------------------
__global__ __launch_bounds__(256) void scan_bsums_kernel(
    int* __restrict__ bsum, int* __restrict__ start_n, int nb)
{
    __shared__ int wsum[4];
    const int t = threadIdx.x, lane = t & 63, wid = t >> 6;
    const int v = (t < nb) ? bsum[t] : 0;
    int incl = v;
#pragma unroll
    for (int off = 1; off < 64; off <<= 1) {
        const int u = __shfl_up(incl, off, 64);
        if (lane >= off) incl += u;
    }
    if (lane == 63) wsum[wid] = incl;
    __syncthreads();
    if (t == 0) {
        int run = 0;
#pragma unroll
        for (int w = 0; w < 4; ++w) { const int s = wsum[w]; wsum[w] = run; run += s; }
        *start_n = run;                   // = E
    }
    __syncthreads();
    if (t < nb) bsum[t] = wsum[wid] + incl - v;
}

// ---------------------------------------------------------------------------
// scan phase 3: add block offsets; produce start[] and cursor[]
// ---------------------------------------------------------------------------
__global__ __launch_bounds__(256) void scan_add_kernel(
    int* __restrict__ startv, int* __restrict__ cursor,
    const int* __restrict__ bsum, int n)
{
    const int i = blockIdx.x * 256 + threadIdx.x;
    if (i < n) {
        const int val = startv[i] + bsum[i >> 8];
        startv[i] = val;
        cursor[i] = val;
    }
}

// ---------------------------------------------------------------------------
// scatter edges into CSR buckets (int atomics)
// ---------------------------------------------------------------------------
__global__ __launch_bounds__(256) void scatter_kernel(
    const int* __restrict__ src, const int* __restrict__ dst,
    int* __restrict__ cursor, int* __restrict__ csr_src, int E)
{
    const int e = blockIdx.x * 256 + threadIdx.x;
    if (e < E) {
        const int pos = atomicAdd(&cursor[dst[e]], 1);
        csr_src[pos] = src[e];
    }
}

// ---------------------------------------------------------------------------
// per-node mean aggregation over bf16 x: 1 wave per node, 2 cols/lane.
// Gather is 256B contiguous per edge (64 lanes x 4B).
// ---------------------------------------------------------------------------
__global__ __launch_bounds__(256) void aggregate_kernel(
    const unsigned short* __restrict__ xb,
    const int* __restrict__ start,
    const int* __restrict__ csr_src,
    unsigned short* __restrict__ meanb)
{
    const int wid = threadIdx.x >> 6;
    const int lane = threadIdx.x & 63;
    const int node = blockIdx.x * 4 + wid;

    const int s0 = start[node];
    const int s1 = start[node + 1];
    float a0 = 0.f, a1 = 0.f;
    for (int j = s0; j < s1; ++j) {
        const int s = csr_src[j];
        const unsigned v =
            *reinterpret_cast<const unsigned*>(&xb[(size_t)s * F + 2 * lane]);
        a0 += __uint_as_float(v << 16);
        a1 += __uint_as_float(v & 0xFFFF0000u);
    }
    const int d = s1 - s0;
    const float inv = (d > 0) ? (1.0f / (float)d) : 1.0f;
    const unsigned out =
        (unsigned)f2bf(a0 * inv) | ((unsigned)f2bf(a1 * inv) << 16);
    *reinterpret_cast<unsigned*>(&meanb[(size_t)node * F + 2 * lane]) = out;
}

// ---------------------------------------------------------------------------
// out = [mean | x]_bf16 @ Bt^T + b  via mfma_f32_16x16x32_bf16.
// Block = 256 thr = 4 waves; block tile 64 rows x 128 cols; wave: 16 rows.
// A-frag: lane holds A[mbase+(l&15)][s*32+(l>>4)*8 + j], 16B contiguous.
// B-frag: lane holds B[k][col] = Bt[col*256+k...], 16B contiguous.
// ---------------------------------------------------------------------------
__global__ __launch_bounds__(256) void out_mfma_kernel(
    const unsigned short* __restrict__ meanb,
    const unsigned short* __restrict__ xb,
    const unsigned short* __restrict__ Bt,
    const float* __restrict__ bias,
    float* __restrict__ out)
{
    const int t = threadIdx.x, lane = t & 63, wid = t >> 6;
    const int mbase = blockIdx.x * 64 + wid * 16;
    const int arow = mbase + (lane & 15);
    const int kchunk = (lane >> 4) * 8;
    const bool rowok = arow < N_NODES;

    f32x4 acc[8];
#pragma unroll
    for (int nt = 0; nt < 8; ++nt) acc[nt] = (f32x4){0.f, 0.f, 0.f, 0.f};

#pragma unroll
    for (int s = 0; s < 8; ++s) {
        const int k = s * 32 + kchunk;
        bf16x8 a = (bf16x8){0, 0, 0, 0, 0, 0, 0, 0};
        if (rowok) {
            const unsigned short* p = (k < F)
                ? &meanb[(size_t)arow * F + k]
                : &xb[(size_t)arow * F + (k - F)];
            a = *reinterpret_cast<const bf16x8*>(p);
        }
#pragma unroll
        for (int nt = 0; nt < 8; ++nt) {
            const bf16x8 bf = *reinterpret_cast<const bf16x8*>(
                &Bt[(size_t)(nt * 16 + (lane & 15)) * 256 + s * 32 + kchunk]);
            acc[nt] = __builtin_amdgcn_mfma_f32_16x16x32_bf16(a, bf, acc[nt], 0, 0, 0);
        }
    }

    const int crow0 = mbase + (lane >> 4) * 4;
    const int ccol = lane & 15;
#pragma unroll
    for (int nt = 0; nt < 8; ++nt) {
        const int col = nt * 16 + ccol;
        const float bv = bias[col];
#pragma unroll
        for (int r = 0; r < 4; ++r) {
            const int row = crow0 + r;
            if (row < N_NODES) out[(size_t)row * F + col] = acc[nt][r] + bv;
        }
    }
}

extern "C" void kernel_launch(void* const* d_in, const int* in_sizes, int n_in,
                              void* d_out, int out_size, void* d_ws, size_t ws_size,
                              hipStream_t stream)
{
    const float* x  = (const float*)d_in[0];
    const int*   ei = (const int*)d_in[1];
    const float* Wl = (const float*)d_in[2];
    const float* Wr = (const float*)d_in[3];
    const float* b  = (const float*)d_in[4];
    float* out = (float*)d_out;

    const int E = in_sizes[1] / 2;           // 800000
    const int* src = ei;
    const int* dst = ei + E;

    // Workspace layout.
    int* deg     = (int*)d_ws;               // 50048
    int* start   = deg + 50048;              // 50064 (50001 used)
    int* cursor  = start + 50064;            // 50048
    int* bsum    = cursor + 50048;           // 256
    int* csr_src = bsum + 256;               // 800000
    unsigned short* xb    = (unsigned short*)(csr_src + 800000);  // 6.4M
    unsigned short* meanb = xb + (size_t)N_NODES * F;             // 6.4M
    unsigned short* Bt    = meanb + (size_t)N_NODES * F;          // 32768

    hipMemsetAsync(deg, 0, (size_t)N_NODES * sizeof(int), stream);

    convert_x_kernel<<<(N_NODES * F / 4 + 255) / 256, 256, 0, stream>>>(
        x, xb, N_NODES * F / 4);
    convert_bt_kernel<<<128, 256, 0, stream>>>(Wl, Wr, Bt);

    hist_kernel<<<(E + 255) / 256, 256, 0, stream>>>(dst, deg, E);

    const int nb = (N_NODES + 255) / 256;    // 196
    scan_local_kernel<<<nb, 256, 0, stream>>>(deg, start, bsum, N_NODES);
    scan_bsums_kernel<<<1, 256, 0, stream>>>(bsum, start + N_NODES, nb);
    scan_add_kernel<<<nb, 256, 0, stream>>>(start, cursor, bsum, N_NODES);

    scatter_kernel<<<(E + 255) / 256, 256, 0, stream>>>(src, dst, cursor, csr_src, E);

    aggregate_kernel<<<N_NODES / 4, 256, 0, stream>>>(xb, start, csr_src, meanb);

    out_mfma_kernel<<<(N_NODES + 63) / 64, 256, 0, stream>>>(
        meanb, xb, Bt, b, out);
}

// Round 6
// 147.782 us; speedup vs baseline: 5.5910x; 1.5185x over previous
//
#include <hip/hip_runtime.h>

#define N_NODES 50000
#define F 128

typedef __attribute__((ext_vector_type(8))) short bf16x8;
typedef __attribute__((ext_vector_type(4))) float f32x4;

__device__ __forceinline__ unsigned short f2bf(float f) {
    unsigned u = __float_as_uint(f);
    unsigned r = u + 0x7FFFu + ((u >> 16) & 1u);   // RNE
    return (unsigned short)(r >> 16);
}

// ---------------------------------------------------------------------------
// x (fp32, N x 128) -> bf16
// ---------------------------------------------------------------------------
__global__ __launch_bounds__(256) void convert_x_kernel(
    const float* __restrict__ x, unsigned short* __restrict__ xb, int n4)
{
    const int i = blockIdx.x * 256 + threadIdx.x;
    if (i < n4) {
        const float4 v = reinterpret_cast<const float4*>(x)[i];
        ushort4 o;
        o.x = f2bf(v.x); o.y = f2bf(v.y); o.z = f2bf(v.z); o.w = f2bf(v.w);
        reinterpret_cast<ushort4*>(xb)[i] = o;
    }
}

// ---------------------------------------------------------------------------
// Bt[n][k] = bf16( k<128 ? Wl[k][n] : Wr[k-128][n] )   (128 x 256, K-contig)
// ---------------------------------------------------------------------------
__global__ __launch_bounds__(256) void convert_bt_kernel(
    const float* __restrict__ Wl, const float* __restrict__ Wr,
    unsigned short* __restrict__ Bt)
{
    const int gid = blockIdx.x * 256 + threadIdx.x;   // 32768 total
    const int n = gid >> 8;
    const int k = gid & 255;
    const float v = (k < F) ? Wl[k * F + n] : Wr[(k - F) * F + n];
    Bt[gid] = f2bf(v);
}

// ---------------------------------------------------------------------------
// degree histogram + per-edge rank (int atomics; rank write coalesced)
// ---------------------------------------------------------------------------
__global__ __launch_bounds__(256) void hist_kernel(
    const int* __restrict__ dst, int* __restrict__ deg,
    int* __restrict__ rank, int E)
{
    const int e = blockIdx.x * 256 + threadIdx.x;
    if (e < E) rank[e] = atomicAdd(&deg[dst[e]], 1);
}

// ---------------------------------------------------------------------------
// scan phase 1: per-block (256-wide) exclusive scan + block sums
// ---------------------------------------------------------------------------
__global__ __launch_bounds__(256) void scan_local_kernel(
    const int* __restrict__ deg, int* __restrict__ excl,
    int* __restrict__ bsum, int n)
{
    __shared__ int wsum[4];
    const int t = threadIdx.x, lane = t & 63, wid = t >> 6;
    const int i = blockIdx.x * 256 + t;
    const int v = (i < n) ? deg[i] : 0;
    int incl = v;
#pragma unroll
    for (int off = 1; off < 64; off <<= 1) {
        const int u = __shfl_up(incl, off, 64);
        if (lane >= off) incl += u;
    }
    if (lane == 63) wsum[wid] = incl;
    __syncthreads();
    if (t == 0) {
        int run = 0;
#pragma unroll
        for (int w = 0; w < 4; ++w) { const int s = wsum[w]; wsum[w] = run; run += s; }
        bsum[blockIdx.x] = run;
    }
    __syncthreads();
    if (i < n) excl[i] = wsum[wid] + incl - v;
}

// ---------------------------------------------------------------------------
// scan phase 2: exclusive scan of the <=256 block sums; writes grand total
// ---------------------------------------------------------------------------
__global__ __launch_bounds__(256) void scan_bsums_kernel(
    int* __restrict__ bsum, int* __restrict__ start_n, int nb)
{
    __shared__ int wsum[4];
    const int t = threadIdx.x, lane = t & 63, wid = t >> 6;
    const int v = (t < nb) ? bsum[t] : 0;
    int incl = v;
#pragma unroll
    for (int off = 1; off < 64; off <<= 1) {
        const int u = __shfl_up(incl, off, 64);
        if (lane >= off) incl += u;
    }
    if (lane == 63) wsum[wid] = incl;
    __syncthreads();
    if (t == 0) {
        int run = 0;
#pragma unroll
        for (int w = 0; w < 4; ++w) { const int s = wsum[w]; wsum[w] = run; run += s; }
        *start_n = run;                   // = E
    }
    __syncthreads();
    if (t < nb) bsum[t] = wsum[wid] + incl - v;
}

// ---------------------------------------------------------------------------
// scan phase 3: add block offsets -> start[]
// ---------------------------------------------------------------------------
__global__ __launch_bounds__(256) void scan_add_kernel(
    int* __restrict__ startv, const int* __restrict__ bsum, int n)
{
    const int i = blockIdx.x * 256 + threadIdx.x;
    if (i < n) startv[i] += bsum[i >> 8];
}

// ---------------------------------------------------------------------------
// scatter edges into CSR buckets — NO atomics (rank precomputed)
// ---------------------------------------------------------------------------
__global__ __launch_bounds__(256) void scatter_kernel(
    const int* __restrict__ src, const int* __restrict__ dst,
    const int* __restrict__ rank, const int* __restrict__ start,
    int* __restrict__ csr_src, int E)
{
    const int e = blockIdx.x * 256 + threadIdx.x;
    if (e < E) {
        csr_src[start[dst[e]] + rank[e]] = src[e];
    }
}

// ---------------------------------------------------------------------------
// per-node mean aggregation over bf16 x: 1 wave per node, 2 cols/lane.
// Neighbor indices preloaded cooperatively (64 at a time, one coalesced
// 256B load), shfl-broadcast, row gathers unrolled x4 for MLP.
// ---------------------------------------------------------------------------
__global__ __launch_bounds__(256) void aggregate_kernel(
    const unsigned short* __restrict__ xb,
    const int* __restrict__ start,
    const int* __restrict__ csr_src,
    unsigned short* __restrict__ meanb)
{
    const int wid = threadIdx.x >> 6;
    const int lane = threadIdx.x & 63;
    const int node = blockIdx.x * 4 + wid;

    const int s0 = start[node];
    const int s1 = start[node + 1];
    float a0 = 0.f, a1 = 0.f;

    const int coloff = 2 * lane;

    for (int base = s0; base < s1; base += 64) {
        const int cnt = min(64, s1 - base);
        const int myidx = (base + lane < s1) ? csr_src[base + lane] : 0;

        int j = 0;
        for (; j + 4 <= cnt; j += 4) {
            const int i0 = __shfl(myidx, j + 0);
            const int i1 = __shfl(myidx, j + 1);
            const int i2 = __shfl(myidx, j + 2);
            const int i3 = __shfl(myidx, j + 3);
            const unsigned v0 = *reinterpret_cast<const unsigned*>(&xb[(size_t)i0 * F + coloff]);
            const unsigned v1 = *reinterpret_cast<const unsigned*>(&xb[(size_t)i1 * F + coloff]);
            const unsigned v2 = *reinterpret_cast<const unsigned*>(&xb[(size_t)i2 * F + coloff]);
            const unsigned v3 = *reinterpret_cast<const unsigned*>(&xb[(size_t)i3 * F + coloff]);
            a0 += __uint_as_float(v0 << 16);
            a1 += __uint_as_float(v0 & 0xFFFF0000u);
            a0 += __uint_as_float(v1 << 16);
            a1 += __uint_as_float(v1 & 0xFFFF0000u);
            a0 += __uint_as_float(v2 << 16);
            a1 += __uint_as_float(v2 & 0xFFFF0000u);
            a0 += __uint_as_float(v3 << 16);
            a1 += __uint_as_float(v3 & 0xFFFF0000u);
        }
        for (; j < cnt; ++j) {
            const int s = __shfl(myidx, j);
            const unsigned v = *reinterpret_cast<const unsigned*>(&xb[(size_t)s * F + coloff]);
            a0 += __uint_as_float(v << 16);
            a1 += __uint_as_float(v & 0xFFFF0000u);
        }
    }

    const int d = s1 - s0;
    const float inv = (d > 0) ? (1.0f / (float)d) : 1.0f;
    const unsigned out =
        (unsigned)f2bf(a0 * inv) | ((unsigned)f2bf(a1 * inv) << 16);
    *reinterpret_cast<unsigned*>(&meanb[(size_t)node * F + coloff]) = out;
}

// ---------------------------------------------------------------------------
// out = [mean | x]_bf16 @ Bt^T + b  via mfma_f32_16x16x32_bf16.
// Block = 256 thr = 4 waves; block tile 64 rows x 128 cols; wave: 16 rows.
// ---------------------------------------------------------------------------
__global__ __launch_bounds__(256) void out_mfma_kernel(
    const unsigned short* __restrict__ meanb,
    const unsigned short* __restrict__ xb,
    const unsigned short* __restrict__ Bt,
    const float* __restrict__ bias,
    float* __restrict__ out)
{
    const int t = threadIdx.x, lane = t & 63, wid = t >> 6;
    const int mbase = blockIdx.x * 64 + wid * 16;
    const int arow = mbase + (lane & 15);
    const int kchunk = (lane >> 4) * 8;
    const bool rowok = arow < N_NODES;

    f32x4 acc[8];
#pragma unroll
    for (int nt = 0; nt < 8; ++nt) acc[nt] = (f32x4){0.f, 0.f, 0.f, 0.f};

#pragma unroll
    for (int s = 0; s < 8; ++s) {
        const int k = s * 32 + kchunk;
        bf16x8 a = (bf16x8){0, 0, 0, 0, 0, 0, 0, 0};
        if (rowok) {
            const unsigned short* p = (k < F)
                ? &meanb[(size_t)arow * F + k]
                : &xb[(size_t)arow * F + (k - F)];
            a = *reinterpret_cast<const bf16x8*>(p);
        }
#pragma unroll
        for (int nt = 0; nt < 8; ++nt) {
            const bf16x8 bf = *reinterpret_cast<const bf16x8*>(
                &Bt[(size_t)(nt * 16 + (lane & 15)) * 256 + s * 32 + kchunk]);
            acc[nt] = __builtin_amdgcn_mfma_f32_16x16x32_bf16(a, bf, acc[nt], 0, 0, 0);
        }
    }

    const int crow0 = mbase + (lane >> 4) * 4;
    const int ccol = lane & 15;
#pragma unroll
    for (int nt = 0; nt < 8; ++nt) {
        const int col = nt * 16 + ccol;
        const float bv = bias[col];
#pragma unroll
        for (int r = 0; r < 4; ++r) {
            const int row = crow0 + r;
            if (row < N_NODES) out[(size_t)row * F + col] = acc[nt][r] + bv;
        }
    }
}

extern "C" void kernel_launch(void* const* d_in, const int* in_sizes, int n_in,
                              void* d_out, int out_size, void* d_ws, size_t ws_size,
                              hipStream_t stream)
{
    const float* x  = (const float*)d_in[0];
    const int*   ei = (const int*)d_in[1];
    const float* Wl = (const float*)d_in[2];
    const float* Wr = (const float*)d_in[3];
    const float* b  = (const float*)d_in[4];
    float* out = (float*)d_out;

    const int E = in_sizes[1] / 2;           // 800000
    const int* src = ei;
    const int* dst = ei + E;

    // Workspace layout.
    int* deg     = (int*)d_ws;               // 50048
    int* start   = deg + 50048;              // 50064 (50001 used)
    int* bsum    = start + 50064;            // 256
    int* rank    = bsum + 256;               // 800000
    int* csr_src = rank + 800000;            // 800000
    unsigned short* xb    = (unsigned short*)(csr_src + 800000);  // 6.4M
    unsigned short* meanb = xb + (size_t)N_NODES * F;             // 6.4M
    unsigned short* Bt    = meanb + (size_t)N_NODES * F;          // 32768

    hipMemsetAsync(deg, 0, (size_t)N_NODES * sizeof(int), stream);

    convert_x_kernel<<<(N_NODES * F / 4 + 255) / 256, 256, 0, stream>>>(
        x, xb, N_NODES * F / 4);
    convert_bt_kernel<<<128, 256, 0, stream>>>(Wl, Wr, Bt);

    hist_kernel<<<(E + 255) / 256, 256, 0, stream>>>(dst, deg, rank, E);

    const int nb = (N_NODES + 255) / 256;    // 196
    scan_local_kernel<<<nb, 256, 0, stream>>>(deg, start, bsum, N_NODES);
    scan_bsums_kernel<<<1, 256, 0, stream>>>(bsum, start + N_NODES, nb);
    scan_add_kernel<<<nb, 256, 0, stream>>>(start, bsum, N_NODES);

    scatter_kernel<<<(E + 255) / 256, 256, 0, stream>>>(
        src, dst, rank, start, csr_src, E);

    aggregate_kernel<<<N_NODES / 4, 256, 0, stream>>>(xb, start, csr_src, meanb);

    out_mfma_kernel<<<(N_NODES + 63) / 64, 256, 0, stream>>>(
        meanb, xb, Bt, b, out);
}

// Round 7
// 138.803 us; speedup vs baseline: 5.9527x; 1.0647x over previous
//
#include <hip/hip_runtime.h>

#define N_NODES 50000
#define F 128
#define NB_X 6250      /* 50000*128/4 float4 / 256 threads */
#define NB_BT 128

typedef __attribute__((ext_vector_type(8))) short bf16x8;
typedef __attribute__((ext_vector_type(4))) float f32x4;

__device__ __forceinline__ unsigned short f2bf(float f) {
    unsigned u = __float_as_uint(f);
    unsigned r = u + 0x7FFFu + ((u >> 16) & 1u);   // RNE
    return (unsigned short)(r >> 16);
}

// ---------------------------------------------------------------------------
// Fused prep: x->bf16, Bt build (Bt[n][k] = k<128 ? Wl[k][n] : Wr[k-128][n]),
// and deg zero-fill (replaces the 42us graph-captured hipMemsetAsync).
// ---------------------------------------------------------------------------
__global__ __launch_bounds__(256) void prep_kernel(
    const float* __restrict__ x, unsigned short* __restrict__ xb,
    const float* __restrict__ Wl, const float* __restrict__ Wr,
    unsigned short* __restrict__ Bt, int* __restrict__ deg)
{
    const int bid = blockIdx.x;
    const int t = threadIdx.x;
    if (bid < NB_X) {
        const int i = bid * 256 + t;              // exactly 1.6M float4
        const float4 v = reinterpret_cast<const float4*>(x)[i];
        ushort4 o;
        o.x = f2bf(v.x); o.y = f2bf(v.y); o.z = f2bf(v.z); o.w = f2bf(v.w);
        reinterpret_cast<ushort4*>(xb)[i] = o;
        if (i < 50048) deg[i] = 0;
    } else {
        const int gid = (bid - NB_X) * 256 + t;   // 32768 total
        const int n = gid >> 8;
        const int k = gid & 255;
        const float v = (k < F) ? Wl[k * F + n] : Wr[(k - F) * F + n];
        Bt[gid] = f2bf(v);
    }
}

// ---------------------------------------------------------------------------
// degree histogram + per-edge rank (int atomics; rank write coalesced)
// ---------------------------------------------------------------------------
__global__ __launch_bounds__(256) void hist_kernel(
    const int* __restrict__ dst, int* __restrict__ deg,
    int* __restrict__ rank, int E)
{
    const int e = blockIdx.x * 256 + threadIdx.x;
    if (e < E) rank[e] = atomicAdd(&deg[dst[e]], 1);
}

// ---------------------------------------------------------------------------
// scan phase 1: per-block (256-wide) exclusive scan + block sums
// ---------------------------------------------------------------------------
__global__ __launch_bounds__(256) void scan_local_kernel(
    const int* __restrict__ deg, int* __restrict__ excl,
    int* __restrict__ bsum, int n)
{
    __shared__ int wsum[4];
    const int t = threadIdx.x, lane = t & 63, wid = t >> 6;
    const int i = blockIdx.x * 256 + t;
    const int v = (i < n) ? deg[i] : 0;
    int incl = v;
#pragma unroll
    for (int off = 1; off < 64; off <<= 1) {
        const int u = __shfl_up(incl, off, 64);
        if (lane >= off) incl += u;
    }
    if (lane == 63) wsum[wid] = incl;
    __syncthreads();
    if (t == 0) {
        int run = 0;
#pragma unroll
        for (int w = 0; w < 4; ++w) { const int s = wsum[w]; wsum[w] = run; run += s; }
        bsum[blockIdx.x] = run;
    }
    __syncthreads();
    if (i < n) excl[i] = wsum[wid] + incl - v;
}

// ---------------------------------------------------------------------------
// scan phase 2: exclusive scan of the <=256 block sums; writes grand total
// ---------------------------------------------------------------------------
__global__ __launch_bounds__(256) void scan_bsums_kernel(
    int* __restrict__ bsum, int* __restrict__ start_n, int nb)
{
    __shared__ int wsum[4];
    const int t = threadIdx.x, lane = t & 63, wid = t >> 6;
    const int v = (t < nb) ? bsum[t] : 0;
    int incl = v;
#pragma unroll
    for (int off = 1; off < 64; off <<= 1) {
        const int u = __shfl_up(incl, off, 64);
        if (lane >= off) incl += u;
    }
    if (lane == 63) wsum[wid] = incl;
    __syncthreads();
    if (t == 0) {
        int run = 0;
#pragma unroll
        for (int w = 0; w < 4; ++w) { const int s = wsum[w]; wsum[w] = run; run += s; }
        *start_n = run;                   // = E
    }
    __syncthreads();
    if (t < nb) bsum[t] = wsum[wid] + incl - v;
}

// ---------------------------------------------------------------------------
// scan phase 3: add block offsets -> start[]
// ---------------------------------------------------------------------------
__global__ __launch_bounds__(256) void scan_add_kernel(
    int* __restrict__ startv, const int* __restrict__ bsum, int n)
{
    const int i = blockIdx.x * 256 + threadIdx.x;
    if (i < n) startv[i] += bsum[i >> 8];
}

// ---------------------------------------------------------------------------
// scatter edges into CSR buckets — NO atomics (rank precomputed)
// ---------------------------------------------------------------------------
__global__ __launch_bounds__(256) void scatter_kernel(
    const int* __restrict__ src, const int* __restrict__ dst,
    const int* __restrict__ rank, const int* __restrict__ start,
    int* __restrict__ csr_src, int E)
{
    const int e = blockIdx.x * 256 + threadIdx.x;
    if (e < E) {
        csr_src[start[dst[e]] + rank[e]] = src[e];
    }
}

// ---------------------------------------------------------------------------
// per-node mean aggregation over bf16 x: 1 wave per node, 2 cols/lane.
// Neighbor indices preloaded cooperatively, shfl-broadcast, unrolled x4.
// ---------------------------------------------------------------------------
__global__ __launch_bounds__(256) void aggregate_kernel(
    const unsigned short* __restrict__ xb,
    const int* __restrict__ start,
    const int* __restrict__ csr_src,
    unsigned short* __restrict__ meanb)
{
    const int wid = threadIdx.x >> 6;
    const int lane = threadIdx.x & 63;
    const int node = blockIdx.x * 4 + wid;

    const int s0 = start[node];
    const int s1 = start[node + 1];
    float a0 = 0.f, a1 = 0.f;

    const int coloff = 2 * lane;

    for (int base = s0; base < s1; base += 64) {
        const int cnt = min(64, s1 - base);
        const int myidx = (base + lane < s1) ? csr_src[base + lane] : 0;

        int j = 0;
        for (; j + 4 <= cnt; j += 4) {
            const int i0 = __shfl(myidx, j + 0);
            const int i1 = __shfl(myidx, j + 1);
            const int i2 = __shfl(myidx, j + 2);
            const int i3 = __shfl(myidx, j + 3);
            const unsigned v0 = *reinterpret_cast<const unsigned*>(&xb[(size_t)i0 * F + coloff]);
            const unsigned v1 = *reinterpret_cast<const unsigned*>(&xb[(size_t)i1 * F + coloff]);
            const unsigned v2 = *reinterpret_cast<const unsigned*>(&xb[(size_t)i2 * F + coloff]);
            const unsigned v3 = *reinterpret_cast<const unsigned*>(&xb[(size_t)i3 * F + coloff]);
            a0 += __uint_as_float(v0 << 16);
            a1 += __uint_as_float(v0 & 0xFFFF0000u);
            a0 += __uint_as_float(v1 << 16);
            a1 += __uint_as_float(v1 & 0xFFFF0000u);
            a0 += __uint_as_float(v2 << 16);
            a1 += __uint_as_float(v2 & 0xFFFF0000u);
            a0 += __uint_as_float(v3 << 16);
            a1 += __uint_as_float(v3 & 0xFFFF0000u);
        }
        for (; j < cnt; ++j) {
            const int s = __shfl(myidx, j);
            const unsigned v = *reinterpret_cast<const unsigned*>(&xb[(size_t)s * F + coloff]);
            a0 += __uint_as_float(v << 16);
            a1 += __uint_as_float(v & 0xFFFF0000u);
        }
    }

    const int d = s1 - s0;
    const float inv = (d > 0) ? (1.0f / (float)d) : 1.0f;
    const unsigned out =
        (unsigned)f2bf(a0 * inv) | ((unsigned)f2bf(a1 * inv) << 16);
    *reinterpret_cast<unsigned*>(&meanb[(size_t)node * F + coloff]) = out;
}

// ---------------------------------------------------------------------------
// out = [mean | x]_bf16 @ Bt^T + b  via mfma_f32_16x16x32_bf16.
// Block = 4 waves; block tile 64 rows x 128 cols; wave owns 16 rows.
// C staged per-wave in LDS (pad 132 -> <=2-way banks), written as full
// 512B rows of float4 (coalesced), replacing the 64B-segment scatter.
// ---------------------------------------------------------------------------
__global__ __launch_bounds__(256) void out_mfma_kernel(
    const unsigned short* __restrict__ meanb,
    const unsigned short* __restrict__ xb,
    const unsigned short* __restrict__ Bt,
    const float* __restrict__ bias,
    float* __restrict__ out)
{
    __shared__ float cs[4][16][132];

    const int t = threadIdx.x, lane = t & 63, wid = t >> 6;
    const int mbase = blockIdx.x * 64 + wid * 16;
    const int arow = mbase + (lane & 15);
    const int kchunk = (lane >> 4) * 8;
    const bool rowok = arow < N_NODES;

    f32x4 acc[8];
#pragma unroll
    for (int nt = 0; nt < 8; ++nt) acc[nt] = (f32x4){0.f, 0.f, 0.f, 0.f};

#pragma unroll
    for (int s = 0; s < 8; ++s) {
        const int k = s * 32 + kchunk;
        bf16x8 a = (bf16x8){0, 0, 0, 0, 0, 0, 0, 0};
        if (rowok) {
            const unsigned short* p = (k < F)
                ? &meanb[(size_t)arow * F + k]
                : &xb[(size_t)arow * F + (k - F)];
            a = *reinterpret_cast<const bf16x8*>(p);
        }
#pragma unroll
        for (int nt = 0; nt < 8; ++nt) {
            const bf16x8 bf = *reinterpret_cast<const bf16x8*>(
                &Bt[(size_t)(nt * 16 + (lane & 15)) * 256 + s * 32 + kchunk]);
            acc[nt] = __builtin_amdgcn_mfma_f32_16x16x32_bf16(a, bf, acc[nt], 0, 0, 0);
        }
    }

    // Stage C (+bias) into this wave's LDS tile.  Only the owning wave
    // touches cs[wid] -> no __syncthreads needed (lgkmcnt handles RAW).
    const int crow_local = (lane >> 4) * 4;
    const int ccol = lane & 15;
#pragma unroll
    for (int nt = 0; nt < 8; ++nt) {
        const int col = nt * 16 + ccol;
        const float bv = bias[col];
#pragma unroll
        for (int r = 0; r < 4; ++r)
            cs[wid][crow_local + r][col] = acc[nt][r] + bv;
    }

    // Coalesced write: half-wave writes one full 512B row per step.
#pragma unroll
    for (int i = 0; i < 8; ++i) {
        const int idx = lane + i * 64;        // 0..511
        const int r = idx >> 5;               // 0..15
        const int c4 = (idx & 31) << 2;       // 0..124
        const int grow = mbase + r;
        if (grow < N_NODES) {
            float4 v;
            v.x = cs[wid][r][c4 + 0];
            v.y = cs[wid][r][c4 + 1];
            v.z = cs[wid][r][c4 + 2];
            v.w = cs[wid][r][c4 + 3];
            *reinterpret_cast<float4*>(&out[(size_t)grow * F + c4]) = v;
        }
    }
}

extern "C" void kernel_launch(void* const* d_in, const int* in_sizes, int n_in,
                              void* d_out, int out_size, void* d_ws, size_t ws_size,
                              hipStream_t stream)
{
    const float* x  = (const float*)d_in[0];
    const int*   ei = (const int*)d_in[1];
    const float* Wl = (const float*)d_in[2];
    const float* Wr = (const float*)d_in[3];
    const float* b  = (const float*)d_in[4];
    float* out = (float*)d_out;

    const int E = in_sizes[1] / 2;           // 800000
    const int* src = ei;
    const int* dst = ei + E;

    // Workspace layout.
    int* deg     = (int*)d_ws;               // 50048
    int* start   = deg + 50048;              // 50064 (50001 used)
    int* bsum    = start + 50064;            // 256
    int* rank    = bsum + 256;               // 800000
    int* csr_src = rank + 800000;            // 800000
    unsigned short* xb    = (unsigned short*)(csr_src + 800000);  // 6.4M
    unsigned short* meanb = xb + (size_t)N_NODES * F;             // 6.4M
    unsigned short* Bt    = meanb + (size_t)N_NODES * F;          // 32768

    prep_kernel<<<NB_X + NB_BT, 256, 0, stream>>>(x, xb, Wl, Wr, Bt, deg);

    hist_kernel<<<(E + 255) / 256, 256, 0, stream>>>(dst, deg, rank, E);

    const int nb = (N_NODES + 255) / 256;    // 196
    scan_local_kernel<<<nb, 256, 0, stream>>>(deg, start, bsum, N_NODES);
    scan_bsums_kernel<<<1, 256, 0, stream>>>(bsum, start + N_NODES, nb);
    scan_add_kernel<<<nb, 256, 0, stream>>>(start, bsum, N_NODES);

    scatter_kernel<<<(E + 255) / 256, 256, 0, stream>>>(
        src, dst, rank, start, csr_src, E);

    aggregate_kernel<<<N_NODES / 4, 256, 0, stream>>>(xb, start, csr_src, meanb);

    out_mfma_kernel<<<(N_NODES + 63) / 64, 256, 0, stream>>>(
        meanb, xb, Bt, b, out);
}

// Round 8
// 137.062 us; speedup vs baseline: 6.0283x; 1.0127x over previous
//
#include <hip/hip_runtime.h>

#define N_NODES 50000
#define F 128
#define NB_X 6250      /* 50000*128/4 float4 / 256 threads */
#define NB_HIST 3125   /* 800000 / 256 */
#define NB_BT 128

typedef __attribute__((ext_vector_type(8))) short bf16x8;
typedef __attribute__((ext_vector_type(4))) float f32x4;

__device__ __forceinline__ unsigned short f2bf(float f) {
    unsigned u = __float_as_uint(f);
    unsigned r = u + 0x7FFFu + ((u >> 16) & 1u);   // RNE
    return (unsigned short)(r >> 16);
}

// ---------------------------------------------------------------------------
// deg zero-fill (must precede hist atomics)
// ---------------------------------------------------------------------------
__global__ __launch_bounds__(256) void zero_deg_kernel(int* __restrict__ deg)
{
    const int i = blockIdx.x * 256 + threadIdx.x;
    if (i < 50048) deg[i] = 0;
}

// ---------------------------------------------------------------------------
// Fused: x->bf16 convert  +  degree histogram/rank  +  Bt build.
// Block roles interleaved 2:1 (convert:hist) so streaming convert blocks
// co-reside with atomic-bound hist blocks and hide the RMW latency.
// ---------------------------------------------------------------------------
__global__ __launch_bounds__(256) void fused_prep_hist_kernel(
    const float* __restrict__ x, unsigned short* __restrict__ xb,
    const int* __restrict__ dst, int* __restrict__ deg, int* __restrict__ rank,
    const float* __restrict__ Wl, const float* __restrict__ Wr,
    unsigned short* __restrict__ Bt, int E)
{
    const int bid = blockIdx.x;
    const int t = threadIdx.x;
    if (bid < 3 * NB_HIST) {
        const int slot = bid % 3;
        const int grp = bid / 3;
        if (slot < 2) {
            // convert block index 0..6249
            const int i = (grp * 2 + slot) * 256 + t;
            const float4 v = reinterpret_cast<const float4*>(x)[i];
            ushort4 o;
            o.x = f2bf(v.x); o.y = f2bf(v.y); o.z = f2bf(v.z); o.w = f2bf(v.w);
            reinterpret_cast<ushort4*>(xb)[i] = o;
        } else {
            const int e = grp * 256 + t;
            if (e < E) rank[e] = atomicAdd(&deg[dst[e]], 1);
        }
    } else {
        const int gid = (bid - 3 * NB_HIST) * 256 + t;   // 32768 total
        const int n = gid >> 8;
        const int k = gid & 255;
        const float v = (k < F) ? Wl[k * F + n] : Wr[(k - F) * F + n];
        Bt[gid] = f2bf(v);
    }
}

// ---------------------------------------------------------------------------
// scan phase 1: per-block (256-wide) exclusive scan + block sums
// ---------------------------------------------------------------------------
__global__ __launch_bounds__(256) void scan_local_kernel(
    const int* __restrict__ deg, int* __restrict__ excl,
    int* __restrict__ bsum, int n)
{
    __shared__ int wsum[4];
    const int t = threadIdx.x, lane = t & 63, wid = t >> 6;
    const int i = blockIdx.x * 256 + t;
    const int v = (i < n) ? deg[i] : 0;
    int incl = v;
#pragma unroll
    for (int off = 1; off < 64; off <<= 1) {
        const int u = __shfl_up(incl, off, 64);
        if (lane >= off) incl += u;
    }
    if (lane == 63) wsum[wid] = incl;
    __syncthreads();
    if (t == 0) {
        int run = 0;
#pragma unroll
        for (int w = 0; w < 4; ++w) { const int s = wsum[w]; wsum[w] = run; run += s; }
        bsum[blockIdx.x] = run;
    }
    __syncthreads();
    if (i < n) excl[i] = wsum[wid] + incl - v;
}

// ---------------------------------------------------------------------------
// scan phase 2: exclusive scan of the <=256 block sums; writes grand total
// ---------------------------------------------------------------------------
__global__ __launch_bounds__(256) void scan_bsums_kernel(
    int* __restrict__ bsum, int* __restrict__ start_n, int nb)
{
    __shared__ int wsum[4];
    const int t = threadIdx.x, lane = t & 63, wid = t >> 6;
    const int v = (t < nb) ? bsum[t] : 0;
    int incl = v;
#pragma unroll
    for (int off = 1; off < 64; off <<= 1) {
        const int u = __shfl_up(incl, off, 64);
        if (lane >= off) incl += u;
    }
    if (lane == 63) wsum[wid] = incl;
    __syncthreads();
    if (t == 0) {
        int run = 0;
#pragma unroll
        for (int w = 0; w < 4; ++w) { const int s = wsum[w]; wsum[w] = run; run += s; }
        *start_n = run;                   // = E
    }
    __syncthreads();
    if (t < nb) bsum[t] = wsum[wid] + incl - v;
}

// ---------------------------------------------------------------------------
// scan phase 3: add block offsets -> start[]
// ---------------------------------------------------------------------------
__global__ __launch_bounds__(256) void scan_add_kernel(
    int* __restrict__ startv, const int* __restrict__ bsum, int n)
{
    const int i = blockIdx.x * 256 + threadIdx.x;
    if (i < n) startv[i] += bsum[i >> 8];
}

// ---------------------------------------------------------------------------
// scatter edges into CSR buckets — NO atomics (rank precomputed)
// ---------------------------------------------------------------------------
__global__ __launch_bounds__(256) void scatter_kernel(
    const int* __restrict__ src, const int* __restrict__ dst,
    const int* __restrict__ rank, const int* __restrict__ start,
    int* __restrict__ csr_src, int E)
{
    const int e = blockIdx.x * 256 + threadIdx.x;
    if (e < E) {
        csr_src[start[dst[e]] + rank[e]] = src[e];
    }
}

// ---------------------------------------------------------------------------
// per-node mean aggregation over bf16 x: 1 wave per node, 2 cols/lane.
// Neighbor indices preloaded cooperatively, shfl-broadcast, unrolled x8
// (8 independent 256B row gathers in flight per wave).
// ---------------------------------------------------------------------------
__global__ __launch_bounds__(256) void aggregate_kernel(
    const unsigned short* __restrict__ xb,
    const int* __restrict__ start,
    const int* __restrict__ csr_src,
    unsigned short* __restrict__ meanb)
{
    const int wid = threadIdx.x >> 6;
    const int lane = threadIdx.x & 63;
    const int node = blockIdx.x * 4 + wid;

    const int s0 = start[node];
    const int s1 = start[node + 1];
    float a0 = 0.f, a1 = 0.f;

    const int coloff = 2 * lane;

    for (int base = s0; base < s1; base += 64) {
        const int cnt = min(64, s1 - base);
        const int myidx = (base + lane < s1) ? csr_src[base + lane] : 0;

        int j = 0;
        for (; j + 8 <= cnt; j += 8) {
            const int i0 = __shfl(myidx, j + 0);
            const int i1 = __shfl(myidx, j + 1);
            const int i2 = __shfl(myidx, j + 2);
            const int i3 = __shfl(myidx, j + 3);
            const int i4 = __shfl(myidx, j + 4);
            const int i5 = __shfl(myidx, j + 5);
            const int i6 = __shfl(myidx, j + 6);
            const int i7 = __shfl(myidx, j + 7);
            const unsigned v0 = *reinterpret_cast<const unsigned*>(&xb[(size_t)i0 * F + coloff]);
            const unsigned v1 = *reinterpret_cast<const unsigned*>(&xb[(size_t)i1 * F + coloff]);
            const unsigned v2 = *reinterpret_cast<const unsigned*>(&xb[(size_t)i2 * F + coloff]);
            const unsigned v3 = *reinterpret_cast<const unsigned*>(&xb[(size_t)i3 * F + coloff]);
            const unsigned v4 = *reinterpret_cast<const unsigned*>(&xb[(size_t)i4 * F + coloff]);
            const unsigned v5 = *reinterpret_cast<const unsigned*>(&xb[(size_t)i5 * F + coloff]);
            const unsigned v6 = *reinterpret_cast<const unsigned*>(&xb[(size_t)i6 * F + coloff]);
            const unsigned v7 = *reinterpret_cast<const unsigned*>(&xb[(size_t)i7 * F + coloff]);
            a0 += __uint_as_float(v0 << 16);
            a1 += __uint_as_float(v0 & 0xFFFF0000u);
            a0 += __uint_as_float(v1 << 16);
            a1 += __uint_as_float(v1 & 0xFFFF0000u);
            a0 += __uint_as_float(v2 << 16);
            a1 += __uint_as_float(v2 & 0xFFFF0000u);
            a0 += __uint_as_float(v3 << 16);
            a1 += __uint_as_float(v3 & 0xFFFF0000u);
            a0 += __uint_as_float(v4 << 16);
            a1 += __uint_as_float(v4 & 0xFFFF0000u);
            a0 += __uint_as_float(v5 << 16);
            a1 += __uint_as_float(v5 & 0xFFFF0000u);
            a0 += __uint_as_float(v6 << 16);
            a1 += __uint_as_float(v6 & 0xFFFF0000u);
            a0 += __uint_as_float(v7 << 16);
            a1 += __uint_as_float(v7 & 0xFFFF0000u);
        }
        for (; j < cnt; ++j) {
            const int s = __shfl(myidx, j);
            const unsigned v = *reinterpret_cast<const unsigned*>(&xb[(size_t)s * F + coloff]);
            a0 += __uint_as_float(v << 16);
            a1 += __uint_as_float(v & 0xFFFF0000u);
        }
    }

    const int d = s1 - s0;
    const float inv = (d > 0) ? (1.0f / (float)d) : 1.0f;
    const unsigned out =
        (unsigned)f2bf(a0 * inv) | ((unsigned)f2bf(a1 * inv) << 16);
    *reinterpret_cast<unsigned*>(&meanb[(size_t)node * F + coloff]) = out;
}

// ---------------------------------------------------------------------------
// out = [mean | x]_bf16 @ Bt^T + b  via mfma_f32_16x16x32_bf16.
// Block = 4 waves; block tile 64 rows x 128 cols; wave owns 16 rows.
// C staged per-wave in LDS, written as full 512B float4 rows (coalesced).
// ---------------------------------------------------------------------------
__global__ __launch_bounds__(256) void out_mfma_kernel(
    const unsigned short* __restrict__ meanb,
    const unsigned short* __restrict__ xb,
    const unsigned short* __restrict__ Bt,
    const float* __restrict__ bias,
    float* __restrict__ out)
{
    __shared__ float cs[4][16][132];

    const int t = threadIdx.x, lane = t & 63, wid = t >> 6;
    const int mbase = blockIdx.x * 64 + wid * 16;
    const int arow = mbase + (lane & 15);
    const int kchunk = (lane >> 4) * 8;
    const bool rowok = arow < N_NODES;

    f32x4 acc[8];
#pragma unroll
    for (int nt = 0; nt < 8; ++nt) acc[nt] = (f32x4){0.f, 0.f, 0.f, 0.f};

#pragma unroll
    for (int s = 0; s < 8; ++s) {
        const int k = s * 32 + kchunk;
        bf16x8 a = (bf16x8){0, 0, 0, 0, 0, 0, 0, 0};
        if (rowok) {
            const unsigned short* p = (k < F)
                ? &meanb[(size_t)arow * F + k]
                : &xb[(size_t)arow * F + (k - F)];
            a = *reinterpret_cast<const bf16x8*>(p);
        }
#pragma unroll
        for (int nt = 0; nt < 8; ++nt) {
            const bf16x8 bf = *reinterpret_cast<const bf16x8*>(
                &Bt[(size_t)(nt * 16 + (lane & 15)) * 256 + s * 32 + kchunk]);
            acc[nt] = __builtin_amdgcn_mfma_f32_16x16x32_bf16(a, bf, acc[nt], 0, 0, 0);
        }
    }

    const int crow_local = (lane >> 4) * 4;
    const int ccol = lane & 15;
#pragma unroll
    for (int nt = 0; nt < 8; ++nt) {
        const int col = nt * 16 + ccol;
        const float bv = bias[col];
#pragma unroll
        for (int r = 0; r < 4; ++r)
            cs[wid][crow_local + r][col] = acc[nt][r] + bv;
    }

#pragma unroll
    for (int i = 0; i < 8; ++i) {
        const int idx = lane + i * 64;        // 0..511
        const int r = idx >> 5;               // 0..15
        const int c4 = (idx & 31) << 2;       // 0..124
        const int grow = mbase + r;
        if (grow < N_NODES) {
            float4 v;
            v.x = cs[wid][r][c4 + 0];
            v.y = cs[wid][r][c4 + 1];
            v.z = cs[wid][r][c4 + 2];
            v.w = cs[wid][r][c4 + 3];
            *reinterpret_cast<float4*>(&out[(size_t)grow * F + c4]) = v;
        }
    }
}

extern "C" void kernel_launch(void* const* d_in, const int* in_sizes, int n_in,
                              void* d_out, int out_size, void* d_ws, size_t ws_size,
                              hipStream_t stream)
{
    const float* x  = (const float*)d_in[0];
    const int*   ei = (const int*)d_in[1];
    const float* Wl = (const float*)d_in[2];
    const float* Wr = (const float*)d_in[3];
    const float* b  = (const float*)d_in[4];
    float* out = (float*)d_out;

    const int E = in_sizes[1] / 2;           // 800000
    const int* src = ei;
    const int* dst = ei + E;

    // Workspace layout.
    int* deg     = (int*)d_ws;               // 50048
    int* start   = deg + 50048;              // 50064 (50001 used)
    int* bsum    = start + 50064;            // 256
    int* rank    = bsum + 256;               // 800000
    int* csr_src = rank + 800000;            // 800000
    unsigned short* xb    = (unsigned short*)(csr_src + 800000);  // 6.4M
    unsigned short* meanb = xb + (size_t)N_NODES * F;             // 6.4M
    unsigned short* Bt    = meanb + (size_t)N_NODES * F;          // 32768

    zero_deg_kernel<<<196, 256, 0, stream>>>(deg);

    fused_prep_hist_kernel<<<3 * NB_HIST + NB_BT, 256, 0, stream>>>(
        x, xb, dst, deg, rank, Wl, Wr, Bt, E);

    const int nb = (N_NODES + 255) / 256;    // 196
    scan_local_kernel<<<nb, 256, 0, stream>>>(deg, start, bsum, N_NODES);
    scan_bsums_kernel<<<1, 256, 0, stream>>>(bsum, start + N_NODES, nb);
    scan_add_kernel<<<nb, 256, 0, stream>>>(start, bsum, N_NODES);

    scatter_kernel<<<(E + 255) / 256, 256, 0, stream>>>(
        src, dst, rank, start, csr_src, E);

    aggregate_kernel<<<N_NODES / 4, 256, 0, stream>>>(xb, start, csr_src, meanb);

    out_mfma_kernel<<<(N_NODES + 63) / 64, 256, 0, stream>>>(
        meanb, xb, Bt, b, out);
}